// Round 8
// baseline (314.197 us; speedup 1.0000x reference)
//
#include <hip/hip_runtime.h>

#define WPB    4         // waves per block in spmm (256 threads)
#define SCAN_B 1024
#define P1B    256       // blocks in bucketing passes
#define BKT_SH 8         // 256 rows per bucket

typedef unsigned u32x2 __attribute__((ext_vector_type(2)));
typedef unsigned u32x4 __attribute__((ext_vector_type(4)));
typedef float    f32x4 __attribute__((ext_vector_type(4)));
typedef float    f32x2 __attribute__((ext_vector_type(2)));

// ---------- bf16 helpers ----------
__device__ __forceinline__ unsigned bf16rne(float x) {
  unsigned u = __float_as_uint(x);
  return (u + 0x7fffu + ((u >> 16) & 1u)) >> 16;
}
__device__ __forceinline__ float bf_lo(unsigned g) { return __uint_as_float(g << 16); }
__device__ __forceinline__ float bf_hi(unsigned g) { return __uint_as_float(g & 0xffff0000u); }

// ---------- prep (bf16 table + covered-zero + softmax + terminator) + p1 histogram ----------
__global__ void prep_p1_k(const f32x2* __restrict__ f, unsigned* __restrict__ hb, int nw,
                          const float* __restrict__ a_in, float* __restrict__ a_buf,
                          int* __restrict__ covered, int* __restrict__ row_start,
                          const int* __restrict__ erow, int* __restrict__ bhist,
                          int E, int N, int C, int NB) {
  extern __shared__ int h[];
  const bool dop1 = (blockIdx.x < P1B);
  if (dop1) {
    for (int k = threadIdx.x; k < NB; k += 256) h[k] = 0;
    __syncthreads();
  }
  int i = blockIdx.x * 256 + threadIdx.x;
  if (i < nw) {
    f32x2 v = __builtin_nontemporal_load(f + i);
    hb[i] = bf16rne(v.x) | (bf16rne(v.y) << 16);
  }
  if (i < N) covered[i] = 0;            // zero here; scatter happens in p2
  if (i == 0) {
    row_start[N] = E;
    float x0 = a_in[0], x1 = a_in[1], x2 = a_in[2];
    float m = fmaxf(x0, fmaxf(x1, x2));
    float e0 = expf(x0 - m), e1 = expf(x1 - m), e2 = expf(x2 - m);
    float s = e0 + e1 + e2;
    a_buf[0] = e0 / s; a_buf[1] = e1 / s; a_buf[2] = e2 / s;
  }
  if (dop1) {
    int s = blockIdx.x * C, e = min(E, s + C);
    for (int j = s + threadIdx.x; j < e; j += 256)
      atomicAdd(&h[erow[j] >> BKT_SH], 1);
    __syncthreads();
    for (int k = threadIdx.x; k < NB; k += 256)
      bhist[(size_t)k * P1B + blockIdx.x] = h[k];
  }
}

// ---------- scan stage A ----------
__global__ void scanA_k(const int* __restrict__ cnt, int* __restrict__ incl,
                        int* __restrict__ bsum, int n) {
  __shared__ int tmp[SCAN_B];
  int tid = threadIdx.x;
  int g = blockIdx.x * SCAN_B + tid;
  tmp[tid] = (g < n) ? cnt[g] : 0;
  __syncthreads();
  for (int off = 1; off < SCAN_B; off <<= 1) {
    int t = (tid >= off) ? tmp[tid - off] : 0;
    __syncthreads();
    tmp[tid] += t;
    __syncthreads();
  }
  if (g < n) incl[g] = tmp[tid];
  if (tid == SCAN_B - 1) bsum[blockIdx.x] = tmp[tid];
}

// ---------- scan stage B+C fused ----------
__global__ void scanBC_k(int* __restrict__ boffs, const int* __restrict__ bhist,
                         const int* __restrict__ bsum, int nb, int n) {
  __shared__ int bs[128];
  int tid = threadIdx.x;
  if (tid < 128) bs[tid] = (tid < nb) ? bsum[tid] : 0;
  __syncthreads();
  for (int off = 1; off < 128; off <<= 1) {
    int t = (tid >= off && tid < 128) ? bs[tid - off] : 0;
    __syncthreads();
    if (tid < 128) bs[tid] += t;
    __syncthreads();
  }
  int g = blockIdx.x * SCAN_B + tid;
  if (g < n) {
    int off2 = (blockIdx.x > 0) ? bs[blockIdx.x - 1] : 0;
    boffs[g] = boffs[g] + off2 - bhist[g];
  }
}

// ---------- pass 2: bedge scatter (LDS cursors) + covered scatter ----------
__global__ void p2_k(const int* __restrict__ row, const int* __restrict__ col,
                     const float* __restrict__ val, const int* __restrict__ boffs,
                     int2* __restrict__ bedge, const int* __restrict__ index,
                     int* __restrict__ covered, int E, int N, int C, int NB) {
  extern __shared__ int cur[];
  for (int k = threadIdx.x; k < NB; k += 256)
    cur[k] = boffs[(size_t)k * P1B + blockIdx.x];
  __syncthreads();
  for (int i = blockIdx.x * 256 + threadIdx.x; i < N; i += P1B * 256)
    covered[index[i]] = 1;
  int s = blockIdx.x * C, e = min(E, s + C);
  for (int i = s + threadIdx.x; i < e; i += 256) {
    int r = row[i];
    int p = atomicAdd(&cur[r >> BKT_SH], 1);
    bedge[p] = make_int2(((r & 255) << 24) | col[i], __float_as_int(val[i]));
  }
}

// ---------- pass 3: per-bucket counting sort by row + rowsum -> dis + row_start ----------
__global__ void p3_k(const int2* __restrict__ bedge, const int* __restrict__ boffs,
                     int* __restrict__ row_start, float* __restrict__ dis,
                     int2* __restrict__ pairs, int E, int N, int NB) {
  __shared__ int rcnt[256];
  __shared__ float rsum[256];
  __shared__ int rbase[256];
  __shared__ int tmp[256];
  int kb = blockIdx.x, t = threadIdx.x;
  int base = boffs[(size_t)kb * P1B];
  int end  = (kb + 1 < NB) ? boffs[(size_t)(kb + 1) * P1B] : E;
  rcnt[t] = 0; rsum[t] = 0.f;
  __syncthreads();
  for (int i = base + t; i < end; i += 256) {
    int2 p = bedge[i];
    int rlo = ((unsigned)p.x) >> 24;
    atomicAdd(&rcnt[rlo], 1);
    atomicAdd(&rsum[rlo], __int_as_float(p.y));
  }
  __syncthreads();
  int v = rcnt[t];
  tmp[t] = v;
  __syncthreads();
  for (int off = 1; off < 256; off <<= 1) {
    int u = (t >= off) ? tmp[t - off] : 0;
    __syncthreads();
    tmp[t] += u;
    __syncthreads();
  }
  rbase[t] = tmp[t] - v;
  int r = (kb << BKT_SH) + t;
  if (r < N) {
    row_start[r] = base + rbase[t];
    float s = rsum[t];
    dis[r] = (s > 0.0f) ? rsqrtf(s) : 0.0f;
  }
  __syncthreads();
  rcnt[t] = rbase[t];
  __syncthreads();
  for (int i = base + t; i < end; i += 256) {
    int2 p = bedge[i];
    int rlo = ((unsigned)p.x) >> 24;
    int pos = base + atomicAdd(&rcnt[rlo], 1);
    pairs[pos] = make_int2(p.x & 0xFFFFFF, p.y);
  }
}

// ---------- scale pair values by dis[col] ----------
__global__ void scale_k(int2* __restrict__ pairs, const float* __restrict__ dis, int E) {
  int i = blockIdx.x * 256 + threadIdx.x;
  if (i < E) {
    int2 p = pairs[i];
    p.y = __float_as_int(__int_as_float(p.y) * dis[p.x]);
    pairs[i] = p;
  }
}

// ---------- half-row SpMM body: quarter (16 lanes) per edge, u32x2 gathers (4 bf16) ----------
// Each block owns one feature half (64 feats) selected by blockIdx-derived hoff (0 or 128 B).
// Under round-robin blockIdx%8 -> XCD dispatch, XCDs 0-3 stream only half 0 of the table,
// XCDs 4-7 only half 1 -> per-XCD L2 working set halves (12.8 MB). Correctness does not
// depend on the mapping.
__device__ __forceinline__ void acc4(float v, u32x2 g, float* a) {
  a[0] = fmaf(v, bf_lo(g.x), a[0]); a[1] = fmaf(v, bf_hi(g.x), a[1]);
  a[2] = fmaf(v, bf_lo(g.y), a[2]); a[3] = fmaf(v, bf_hi(g.y), a[3]);
}

__device__ __forceinline__ void spmm_body_h(const int* __restrict__ row_start,
                                            const int2* __restrict__ pairs,
                                            const char* __restrict__ hb,
                                            int row, int lane, unsigned hoff, float* a) {
  int q = lane >> 4;
  unsigned qoff = ((unsigned)(lane & 15) << 3) | hoff;
  int beg = row_start[row], end = row_start[row + 1];
  for (int base = beg; base < end; base += 64) {
    unsigned long long pl = 0;
    if (base + lane < end)
      pl = __builtin_nontemporal_load((const unsigned long long*)(pairs + base + lane));
    int pc = (int)(pl & 0xffffffffu);
    float pv = __uint_as_float((unsigned)(pl >> 32));   // pre-scaled by dis[col]
    int m = end - base; if (m > 64) m = 64;
    for (int j = 0; j < m; j += 16) {
      int   c0 = __shfl(pc, j + q),      c1 = __shfl(pc, j + 4 + q);
      int   c2 = __shfl(pc, j + 8 + q),  c3 = __shfl(pc, j + 12 + q);
      float v0 = __shfl(pv, j + q),      v1 = __shfl(pv, j + 4 + q);
      float v2 = __shfl(pv, j + 8 + q),  v3 = __shfl(pv, j + 12 + q);
      u32x2 g0 = *(const u32x2*)(hb + (((unsigned)c0 << 8) | qoff));
      u32x2 g1 = *(const u32x2*)(hb + (((unsigned)c1 << 8) | qoff));
      u32x2 g2 = *(const u32x2*)(hb + (((unsigned)c2 << 8) | qoff));
      u32x2 g3 = *(const u32x2*)(hb + (((unsigned)c3 << 8) | qoff));
      acc4(v0, g0, a); acc4(v1, g1, a);
      acc4(v2, g2, a); acc4(v3, g3, a);
    }
  }
#pragma unroll
  for (int i = 0; i < 4; ++i) a[i] += __shfl_xor(a[i], 16);
#pragma unroll
  for (int i = 0; i < 4; ++i) a[i] += __shfl_xor(a[i], 32);
}

// ---------- layer 1 (+ fused fixup1 tail) ----------
__global__ void spmm1_k(const int* __restrict__ row_start, const int2* __restrict__ pairs,
                        const float* __restrict__ dis, const unsigned* __restrict__ hB,
                        const int* __restrict__ index, const int* __restrict__ covered,
                        u32x2* __restrict__ hA2, int n) {
  int xcd = blockIdx.x & 7;
  unsigned hoff = (unsigned)(xcd >> 2) << 7;          // 0 or 128 bytes
  int rb = (blockIdx.x >> 3) * 4 + (xcd & 3);
  int wave = rb * WPB + (threadIdx.x >> 6);
  int lane = threadIdx.x & 63;
  if (wave < n) {
    float a[4] = {0.f, 0.f, 0.f, 0.f};
    spmm_body_h(row_start, pairs, (const char*)hB, wave, lane, hoff, a);
    if (lane < 16) {
      float dr = dis[wave];
      u32x2 pk;
      pk.x = bf16rne(a[0] * dr) | (bf16rne(a[1] * dr) << 16);
      pk.y = bf16rne(a[2] * dr) | (bf16rne(a[3] * dr) << 16);
      hA2[(unsigned)index[wave] * 32u + (hoff >> 3) + (unsigned)lane] = pk;
    }
  }
  // fixup1: copy hB row -> hA row for uncovered nodes (no-op for permutation index)
  int gtid = blockIdx.x * 256 + threadIdx.x;
  int stride = gridDim.x * 256;
  const u32x4* s4 = (const u32x4*)hB;
  u32x4* d4 = (u32x4*)hA2;
  for (int v = gtid; v < n; v += stride) {
    if (!covered[v]) {
      for (int d = 0; d < 16; ++d) d4[(size_t)v * 16 + d] = s4[(size_t)v * 16 + d];
    }
  }
}

// ---------- layer 2 fused epilogue (+ fused fixup2 tail) ----------
__global__ void spmm2_k(const int* __restrict__ row_start, const int2* __restrict__ pairs,
                        const float* __restrict__ dis, const u32x2* __restrict__ hA2,
                        const u32x2* __restrict__ hB2, const int* __restrict__ index,
                        const int* __restrict__ covered, const f32x4* __restrict__ feat4,
                        f32x4* __restrict__ out4, const float* __restrict__ ac, int n) {
  int xcd = blockIdx.x & 7;
  unsigned hoff = (unsigned)(xcd >> 2) << 7;
  int rb = (blockIdx.x >> 3) * 4 + (xcd & 3);
  int wave = rb * WPB + (threadIdx.x >> 6);
  int lane = threadIdx.x & 63;
  if (wave < n) {
    float a[4] = {0.f, 0.f, 0.f, 0.f};
    spmm_body_h(row_start, pairs, (const char*)hA2, wave, lane, hoff, a);
    if (lane < 16) {
      float dr = dis[wave];
      unsigned ro = (unsigned)index[wave] * 32u + (hoff >> 3) + (unsigned)lane;
      u32x2 ga = hA2[ro];
      u32x2 gb = __builtin_nontemporal_load(hB2 + ro);
      float c0 = ac[0], c1 = ac[1], c2 = ac[2];
      f32x4 w;
      w.x = fmaf(c2, a[0] * dr, fmaf(c1, bf_lo(ga.x), c0 * bf_lo(gb.x)));
      w.y = fmaf(c2, a[1] * dr, fmaf(c1, bf_hi(ga.x), c0 * bf_hi(gb.x)));
      w.z = fmaf(c2, a[2] * dr, fmaf(c1, bf_lo(ga.y), c0 * bf_lo(gb.y)));
      w.w = fmaf(c2, a[3] * dr, fmaf(c1, bf_hi(ga.y), c0 * bf_hi(gb.y)));
      __builtin_nontemporal_store(w, out4 + ro);
    }
  }
  // fixup2: out row = (a0+a1+a2)*features for uncovered nodes
  int gtid = blockIdx.x * 256 + threadIdx.x;
  int stride = gridDim.x * 256;
  for (int v = gtid; v < n; v += stride) {
    if (!covered[v]) {
      float s = ac[0] + ac[1] + ac[2];
      for (int d = 0; d < 32; ++d) {
        f32x4 f = feat4[(size_t)v * 32 + d];
        f32x4 w; w.x = s * f.x; w.y = s * f.y; w.z = s * f.z; w.w = s * f.w;
        out4[(size_t)v * 32 + d] = w;
      }
    }
  }
}

extern "C" void kernel_launch(void* const* d_in, const int* in_sizes, int n_in,
                              void* d_out, int out_size, void* d_ws, size_t ws_size,
                              hipStream_t stream) {
  const float* features = (const float*)d_in[0];
  const int*   edge_row = (const int*)d_in[1];
  const int*   edge_col = (const int*)d_in[2];
  const float* edge_val = (const float*)d_in[3];
  const int*   index    = (const int*)d_in[4];
  const float* a_in     = (const float*)d_in[5];

  const int E = in_sizes[1];
  const int N = in_sizes[4];
  const int NB = (N + 255) >> BKT_SH;
  const int NBH = NB * P1B;
  const int C = (E + P1B - 1) / P1B;

  float* out = (float*)d_out;

  char* ws = (char*)d_ws;
  size_t off = 0;
  auto carve = [&](size_t bytes) -> char* {
    char* p = ws + off;
    off = (off + bytes + 255) & ~(size_t)255;
    return p;
  };
  float* a_buf     = (float*)carve(16 * sizeof(float));
  float* dis       = (float*)carve((size_t)N * 4);
  int*   covered   = (int*)carve((size_t)N * 4);
  int*   row_start = (int*)carve((size_t)(N + 1) * 4);
  int*   bsum      = (int*)carve(256 * 4);
  int2*  pairs     = (int2*)carve((size_t)E * 8);
  unsigned* hB     = (unsigned*)carve((size_t)N * 64 * 4);
  size_t ov_bytes = (size_t)NBH * 4 * 2 + (size_t)E * 8 + 1024;
  size_t hA_bytes = (size_t)N * 64 * 4;
  char* ovl = carve(ov_bytes > hA_bytes ? ov_bytes : hA_bytes);
  int*  bhist = (int*)ovl;
  int*  boffs = (int*)(ovl + (((size_t)NBH * 4 + 255) & ~(size_t)255));
  int2* bedge = (int2*)(ovl + 2 * (((size_t)NBH * 4 + 255) & ~(size_t)255));
  unsigned* hA = (unsigned*)ovl;
  (void)ws_size; (void)n_in; (void)out_size;

  const int nbE = (E + 255) / 256;
  const int nbW = (N * 64 + 255) / 256;
  const int nbScan = (NBH + SCAN_B - 1) / SCAN_B;
  const size_t ldsB = (size_t)NB * 4;

  prep_p1_k<<<nbW, 256, ldsB, stream>>>((const f32x2*)features, hB, N * 64,
                                        a_in, a_buf, covered, row_start,
                                        edge_row, bhist, E, N, C, NB);
  scanA_k<<<nbScan, SCAN_B, 0, stream>>>(bhist, boffs, bsum, NBH);
  scanBC_k<<<nbScan, SCAN_B, 0, stream>>>(boffs, bhist, bsum, nbScan, NBH);
  p2_k<<<P1B, 256, ldsB, stream>>>(edge_row, edge_col, edge_val, boffs, bedge,
                                   index, covered, E, N, C, NB);
  p3_k<<<NB, 256, 0, stream>>>(bedge, boffs, row_start, dis, pairs, E, N, NB);
  scale_k<<<nbE, 256, 0, stream>>>(pairs, dis, E);

  // split-D spmm: grid pairs (row-block, feature-half) laid out so blockIdx%8
  // maps halves to disjoint XCD sets under round-robin dispatch.
  const int nbRB = (N + WPB - 1) / WPB;
  const int grid = ((nbRB + 3) / 4) * 8;
  spmm1_k<<<grid, 256, 0, stream>>>(row_start, pairs, dis, hB, index, covered,
                                    (u32x2*)hA, N);
  spmm2_k<<<grid, 256, 0, stream>>>(row_start, pairs, dis, (const u32x2*)hA,
                                    (const u32x2*)hB, index, covered,
                                    (const f32x4*)features, (f32x4*)out, a_buf, N);
}

// Round 9
// 210.384 us; speedup vs baseline: 1.4934x; 1.4934x over previous
//
#include <hip/hip_runtime.h>

#define WPB    4         // waves per block in spmm (256 threads)
#define SCAN_B 1024
#define P1B    256       // blocks in bucketing passes
#define BKT_SH 8         // 256 rows per bucket

typedef unsigned u32x4 __attribute__((ext_vector_type(4)));
typedef float    f32x4 __attribute__((ext_vector_type(4)));
typedef float    f32x2 __attribute__((ext_vector_type(2)));

// ---------- bf16 helpers ----------
__device__ __forceinline__ unsigned bf16rne(float x) {
  unsigned u = __float_as_uint(x);
  return (u + 0x7fffu + ((u >> 16) & 1u)) >> 16;
}
__device__ __forceinline__ float bf_lo(unsigned g) { return __uint_as_float(g << 16); }
__device__ __forceinline__ float bf_hi(unsigned g) { return __uint_as_float(g & 0xffff0000u); }

// ---------- prep (bf16 table + covered-zero + softmax + terminator) + p1 histogram ----------
__global__ void prep_p1_k(const f32x2* __restrict__ f, unsigned* __restrict__ hb, int nw,
                          const float* __restrict__ a_in, float* __restrict__ a_buf,
                          int* __restrict__ covered, int* __restrict__ row_start,
                          const int* __restrict__ erow, int* __restrict__ bhist,
                          int E, int N, int C, int NB) {
  extern __shared__ int h[];
  const bool dop1 = (blockIdx.x < P1B);
  if (dop1) {
    for (int k = threadIdx.x; k < NB; k += 256) h[k] = 0;
    __syncthreads();
  }
  int i = blockIdx.x * 256 + threadIdx.x;
  if (i < nw) {
    f32x2 v = __builtin_nontemporal_load(f + i);
    hb[i] = bf16rne(v.x) | (bf16rne(v.y) << 16);
  }
  if (i < N) covered[i] = 0;            // zero here; scatter of 1s happens in p2
  if (i == 0) {
    row_start[N] = E;
    float x0 = a_in[0], x1 = a_in[1], x2 = a_in[2];
    float m = fmaxf(x0, fmaxf(x1, x2));
    float e0 = expf(x0 - m), e1 = expf(x1 - m), e2 = expf(x2 - m);
    float s = e0 + e1 + e2;
    a_buf[0] = e0 / s; a_buf[1] = e1 / s; a_buf[2] = e2 / s;
  }
  if (dop1) {
    int s = blockIdx.x * C, e = min(E, s + C);
    for (int j = s + threadIdx.x; j < e; j += 256)
      atomicAdd(&h[erow[j] >> BKT_SH], 1);
    __syncthreads();
    for (int k = threadIdx.x; k < NB; k += 256)
      bhist[(size_t)k * P1B + blockIdx.x] = h[k];
  }
}

// ---------- scan stage A ----------
__global__ void scanA_k(const int* __restrict__ cnt, int* __restrict__ incl,
                        int* __restrict__ bsum, int n) {
  __shared__ int tmp[SCAN_B];
  int tid = threadIdx.x;
  int g = blockIdx.x * SCAN_B + tid;
  tmp[tid] = (g < n) ? cnt[g] : 0;
  __syncthreads();
  for (int off = 1; off < SCAN_B; off <<= 1) {
    int t = (tid >= off) ? tmp[tid - off] : 0;
    __syncthreads();
    tmp[tid] += t;
    __syncthreads();
  }
  if (g < n) incl[g] = tmp[tid];
  if (tid == SCAN_B - 1) bsum[blockIdx.x] = tmp[tid];
}

// ---------- scan stage B+C fused ----------
__global__ void scanBC_k(int* __restrict__ boffs, const int* __restrict__ bhist,
                         const int* __restrict__ bsum, int nb, int n) {
  __shared__ int bs[128];
  int tid = threadIdx.x;
  if (tid < 128) bs[tid] = (tid < nb) ? bsum[tid] : 0;
  __syncthreads();
  for (int off = 1; off < 128; off <<= 1) {
    int t = (tid >= off && tid < 128) ? bs[tid - off] : 0;
    __syncthreads();
    if (tid < 128) bs[tid] += t;
    __syncthreads();
  }
  int g = blockIdx.x * SCAN_B + tid;
  if (g < n) {
    int off2 = (blockIdx.x > 0) ? bs[blockIdx.x - 1] : 0;
    boffs[g] = boffs[g] + off2 - bhist[g];
  }
}

// ---------- pass 2: bedge scatter (LDS cursors) + covered scatter ----------
__global__ void p2_k(const int* __restrict__ row, const int* __restrict__ col,
                     const float* __restrict__ val, const int* __restrict__ boffs,
                     int2* __restrict__ bedge, const int* __restrict__ index,
                     int* __restrict__ covered, int E, int N, int C, int NB) {
  extern __shared__ int cur[];
  for (int k = threadIdx.x; k < NB; k += 256)
    cur[k] = boffs[(size_t)k * P1B + blockIdx.x];
  __syncthreads();
  for (int i = blockIdx.x * 256 + threadIdx.x; i < N; i += P1B * 256)
    covered[index[i]] = 1;
  int s = blockIdx.x * C, e = min(E, s + C);
  for (int i = s + threadIdx.x; i < e; i += 256) {
    int r = row[i];
    int p = atomicAdd(&cur[r >> BKT_SH], 1);
    bedge[p] = make_int2(((r & 255) << 24) | col[i], __float_as_int(val[i]));
  }
}

// ---------- pass 3: per-bucket counting sort by row + rowsum -> dis + row_start ----------
__global__ void p3_k(const int2* __restrict__ bedge, const int* __restrict__ boffs,
                     int* __restrict__ row_start, float* __restrict__ dis,
                     int2* __restrict__ pairs, int E, int N, int NB) {
  __shared__ int rcnt[256];
  __shared__ float rsum[256];
  __shared__ int rbase[256];
  __shared__ int tmp[256];
  int kb = blockIdx.x, t = threadIdx.x;
  int base = boffs[(size_t)kb * P1B];
  int end  = (kb + 1 < NB) ? boffs[(size_t)(kb + 1) * P1B] : E;
  rcnt[t] = 0; rsum[t] = 0.f;
  __syncthreads();
  for (int i = base + t; i < end; i += 256) {
    int2 p = bedge[i];
    int rlo = ((unsigned)p.x) >> 24;
    atomicAdd(&rcnt[rlo], 1);
    atomicAdd(&rsum[rlo], __int_as_float(p.y));
  }
  __syncthreads();
  int v = rcnt[t];
  tmp[t] = v;
  __syncthreads();
  for (int off = 1; off < 256; off <<= 1) {
    int u = (t >= off) ? tmp[t - off] : 0;
    __syncthreads();
    tmp[t] += u;
    __syncthreads();
  }
  rbase[t] = tmp[t] - v;
  int r = (kb << BKT_SH) + t;
  if (r < N) {
    row_start[r] = base + rbase[t];
    float s = rsum[t];
    dis[r] = (s > 0.0f) ? rsqrtf(s) : 0.0f;
  }
  __syncthreads();
  rcnt[t] = rbase[t];
  __syncthreads();
  for (int i = base + t; i < end; i += 256) {
    int2 p = bedge[i];
    int rlo = ((unsigned)p.x) >> 24;
    int pos = base + atomicAdd(&rcnt[rlo], 1);
    pairs[pos] = make_int2(p.x & 0xFFFFFF, p.y);
  }
}

// ---------- scale pair values by dis[col] (pre-scale: keeps spmm chain short) ----------
__global__ void scale_k(int2* __restrict__ pairs, const float* __restrict__ dis, int E) {
  int i = blockIdx.x * 256 + threadIdx.x;
  if (i < E) {
    int2 p = pairs[i];
    p.y = __float_as_int(__int_as_float(p.y) * dis[p.x]);
    pairs[i] = p;
  }
}

// ---------- quarter-wave SpMM body: 16 lanes/edge, uint4 gathers, 32-bit addressing ----------
__device__ __forceinline__ void acc8(float v, u32x4 g, float* a) {
  a[0] = fmaf(v, bf_lo(g.x), a[0]); a[1] = fmaf(v, bf_hi(g.x), a[1]);
  a[2] = fmaf(v, bf_lo(g.y), a[2]); a[3] = fmaf(v, bf_hi(g.y), a[3]);
  a[4] = fmaf(v, bf_lo(g.z), a[4]); a[5] = fmaf(v, bf_hi(g.z), a[5]);
  a[6] = fmaf(v, bf_lo(g.w), a[6]); a[7] = fmaf(v, bf_hi(g.w), a[7]);
}

__device__ __forceinline__ void spmm_body(const int* __restrict__ row_start,
                                          const int2* __restrict__ pairs,
                                          const char* __restrict__ hb,
                                          int wave, int lane, float* a) {
  int q = lane >> 4;
  unsigned qoff = (unsigned)(lane & 15) << 4;
  int beg = row_start[wave], end = row_start[wave + 1];
  for (int base = beg; base < end; base += 64) {
    unsigned long long pl = 0;
    if (base + lane < end)
      pl = __builtin_nontemporal_load((const unsigned long long*)(pairs + base + lane));
    int pc = (int)(pl & 0xffffffffu);
    float pv = __uint_as_float((unsigned)(pl >> 32));   // pre-scaled by dis[col]
    int m = end - base; if (m > 64) m = 64;
    for (int j = 0; j < m; j += 16) {
      int   c0 = __shfl(pc, j + q),      c1 = __shfl(pc, j + 4 + q);
      int   c2 = __shfl(pc, j + 8 + q),  c3 = __shfl(pc, j + 12 + q);
      float v0 = __shfl(pv, j + q),      v1 = __shfl(pv, j + 4 + q);
      float v2 = __shfl(pv, j + 8 + q),  v3 = __shfl(pv, j + 12 + q);
      u32x4 g0 = *(const u32x4*)(hb + (((unsigned)c0 << 8) | qoff));
      u32x4 g1 = *(const u32x4*)(hb + (((unsigned)c1 << 8) | qoff));
      u32x4 g2 = *(const u32x4*)(hb + (((unsigned)c2 << 8) | qoff));
      u32x4 g3 = *(const u32x4*)(hb + (((unsigned)c3 << 8) | qoff));
      acc8(v0, g0, a); acc8(v1, g1, a);
      acc8(v2, g2, a); acc8(v3, g3, a);
    }
  }
#pragma unroll
  for (int i = 0; i < 8; ++i) a[i] += __shfl_xor(a[i], 16);
#pragma unroll
  for (int i = 0; i < 8; ++i) a[i] += __shfl_xor(a[i], 32);
}

// ---------- layer 1: hA[index[r]] = bf16( dis[r] * sum vals*hB[col] ) ----------
__global__ void spmm1_k(const int* __restrict__ row_start, const int2* __restrict__ pairs,
                        const float* __restrict__ dis, const unsigned* __restrict__ hB,
                        const int* __restrict__ index, u32x4* __restrict__ hA4, int n) {
  int wave = blockIdx.x * WPB + (threadIdx.x >> 6);
  if (wave >= n) return;
  int lane = threadIdx.x & 63;
  float a[8] = {0.f, 0.f, 0.f, 0.f, 0.f, 0.f, 0.f, 0.f};
  spmm_body(row_start, pairs, (const char*)hB, wave, lane, a);
  if ((lane >> 4) == 0) {
    float dr = dis[wave];
    u32x4 pk;
    pk.x = bf16rne(a[0] * dr) | (bf16rne(a[1] * dr) << 16);
    pk.y = bf16rne(a[2] * dr) | (bf16rne(a[3] * dr) << 16);
    pk.z = bf16rne(a[4] * dr) | (bf16rne(a[5] * dr) << 16);
    pk.w = bf16rne(a[6] * dr) | (bf16rne(a[7] * dr) << 16);
    hA4[(unsigned)index[wave] * 16u + (unsigned)(lane & 15)] = pk;
  }
}

// ---------- layer 2 fused epilogue: out = a0*f + a1*hA + a2*acc ----------
__global__ void spmm2_k(const int* __restrict__ row_start, const int2* __restrict__ pairs,
                        const float* __restrict__ dis, const u32x4* __restrict__ hA4,
                        const u32x4* __restrict__ hB4, const int* __restrict__ index,
                        f32x4* __restrict__ out4, const float* __restrict__ ac, int n) {
  int wave = blockIdx.x * WPB + (threadIdx.x >> 6);
  if (wave >= n) return;
  int lane = threadIdx.x & 63;
  float a[8] = {0.f, 0.f, 0.f, 0.f, 0.f, 0.f, 0.f, 0.f};
  spmm_body(row_start, pairs, (const char*)hA4, wave, lane, a);
  if ((lane >> 4) == 0) {
    unsigned ql = lane & 15;
    float dr = dis[wave];
    unsigned ro = (unsigned)index[wave] * 16u + ql;
    u32x4 ga = hA4[ro];
    u32x4 gb = __builtin_nontemporal_load(hB4 + ro);
    float c0 = ac[0], c1 = ac[1], c2 = ac[2];
    f32x4 w0, w1;
    w0.x = fmaf(c2, a[0] * dr, fmaf(c1, bf_lo(ga.x), c0 * bf_lo(gb.x)));
    w0.y = fmaf(c2, a[1] * dr, fmaf(c1, bf_hi(ga.x), c0 * bf_hi(gb.x)));
    w0.z = fmaf(c2, a[2] * dr, fmaf(c1, bf_lo(ga.y), c0 * bf_lo(gb.y)));
    w0.w = fmaf(c2, a[3] * dr, fmaf(c1, bf_hi(ga.y), c0 * bf_hi(gb.y)));
    w1.x = fmaf(c2, a[4] * dr, fmaf(c1, bf_lo(ga.z), c0 * bf_lo(gb.z)));
    w1.y = fmaf(c2, a[5] * dr, fmaf(c1, bf_hi(ga.z), c0 * bf_hi(gb.z)));
    w1.z = fmaf(c2, a[6] * dr, fmaf(c1, bf_lo(ga.w), c0 * bf_lo(gb.w)));
    w1.w = fmaf(c2, a[7] * dr, fmaf(c1, bf_hi(ga.w), c0 * bf_hi(gb.w)));
    unsigned ob = (unsigned)index[wave] * 32u + 2u * ql;
    __builtin_nontemporal_store(w0, out4 + ob);
    __builtin_nontemporal_store(w1, out4 + ob + 1);
  }
}

// ---------- fixups for uncovered nodes (no-op when index is a permutation) ----------
__global__ void fixup1_k(const int* __restrict__ covered, const u32x4* __restrict__ hB4,
                         u32x4* __restrict__ hA4, int n) {
  int v = blockIdx.x * 256 + threadIdx.x;
  if (v >= n || covered[v]) return;
  for (int d = 0; d < 16; ++d) hA4[(size_t)v * 16 + d] = hB4[(size_t)v * 16 + d];
}

__global__ void fixup2_k(const int* __restrict__ covered, const float2* __restrict__ feat,
                         float2* __restrict__ out, const float* __restrict__ a, int n) {
  int v = blockIdx.x * 256 + threadIdx.x;
  if (v >= n || covered[v]) return;
  float s = a[0] + a[1] + a[2];
  for (int d = 0; d < 64; ++d) {
    float2 f = feat[(size_t)v * 64 + d];
    out[(size_t)v * 64 + d] = make_float2(s * f.x, s * f.y);
  }
}

extern "C" void kernel_launch(void* const* d_in, const int* in_sizes, int n_in,
                              void* d_out, int out_size, void* d_ws, size_t ws_size,
                              hipStream_t stream) {
  const float* features = (const float*)d_in[0];
  const int*   edge_row = (const int*)d_in[1];
  const int*   edge_col = (const int*)d_in[2];
  const float* edge_val = (const float*)d_in[3];
  const int*   index    = (const int*)d_in[4];
  const float* a_in     = (const float*)d_in[5];

  const int E = in_sizes[1];
  const int N = in_sizes[4];
  const int NB = (N + 255) >> BKT_SH;
  const int NBH = NB * P1B;
  const int C = (E + P1B - 1) / P1B;

  float* out = (float*)d_out;

  char* ws = (char*)d_ws;
  size_t off = 0;
  auto carve = [&](size_t bytes) -> char* {
    char* p = ws + off;
    off = (off + bytes + 255) & ~(size_t)255;
    return p;
  };
  float* a_buf     = (float*)carve(16 * sizeof(float));
  float* dis       = (float*)carve((size_t)N * 4);
  int*   covered   = (int*)carve((size_t)N * 4);
  int*   row_start = (int*)carve((size_t)(N + 1) * 4);
  int*   bsum      = (int*)carve(256 * 4);
  int2*  pairs     = (int2*)carve((size_t)E * 8);
  unsigned* hB     = (unsigned*)carve((size_t)N * 64 * 4);
  size_t ov_bytes = (size_t)NBH * 4 * 2 + (size_t)E * 8 + 1024;
  size_t hA_bytes = (size_t)N * 64 * 4;
  char* ovl = carve(ov_bytes > hA_bytes ? ov_bytes : hA_bytes);
  int*  bhist = (int*)ovl;
  int*  boffs = (int*)(ovl + (((size_t)NBH * 4 + 255) & ~(size_t)255));
  int2* bedge = (int2*)(ovl + 2 * (((size_t)NBH * 4 + 255) & ~(size_t)255));
  unsigned* hA = (unsigned*)ovl;
  (void)ws_size; (void)n_in; (void)out_size;

  const int nbE = (E + 255) / 256;
  const int nbW = (N * 64 + 255) / 256;
  const int nbScan = (NBH + SCAN_B - 1) / SCAN_B;
  const int nbN = (N + 255) / 256;
  const size_t ldsB = (size_t)NB * 4;

  prep_p1_k<<<nbW, 256, ldsB, stream>>>((const f32x2*)features, hB, N * 64,
                                        a_in, a_buf, covered, row_start,
                                        edge_row, bhist, E, N, C, NB);
  scanA_k<<<nbScan, SCAN_B, 0, stream>>>(bhist, boffs, bsum, NBH);
  scanBC_k<<<nbScan, SCAN_B, 0, stream>>>(boffs, bhist, bsum, nbScan, NBH);
  p2_k<<<P1B, 256, ldsB, stream>>>(edge_row, edge_col, edge_val, boffs, bedge,
                                   index, covered, E, N, C, NB);
  p3_k<<<NB, 256, 0, stream>>>(bedge, boffs, row_start, dis, pairs, E, N, NB);
  scale_k<<<nbE, 256, 0, stream>>>(pairs, dis, E);

  const int nbSpmm = (N + WPB - 1) / WPB;
  spmm1_k<<<nbSpmm, WPB * 64, 0, stream>>>(row_start, pairs, dis, hB, index,
                                           (u32x4*)hA, N);
  fixup1_k<<<nbN, 256, 0, stream>>>(covered, (const u32x4*)hB, (u32x4*)hA, N);
  spmm2_k<<<nbSpmm, WPB * 64, 0, stream>>>(row_start, pairs, dis, (const u32x4*)hA,
                                           (const u32x4*)hB, index, (f32x4*)out,
                                           a_buf, N);
  fixup2_k<<<nbN, 256, 0, stream>>>(covered, (const float2*)features,
                                    (float2*)out, a_buf, N);
}